// Round 11
// baseline (1328.309 us; speedup 1.0000x reference)
//
#include <hip/hip_runtime.h>

// ============================================================================
// ROUND 11: MEASUREMENT ROUND (zero pipeline risk). r10 = 694.3us is kept
// byte-identical; added h0diag2 = the CURRENT wave-per-row h0 x6 reps over
// shifted rows (1.97GB), dump sink -> surfaces in top-5 with counters.
// t_h0 = dur(h0diag2)/6. Ledger: gather 95 (floor), gemm ~25 (floor),
// fills ~400-430 fixed, mega ~100-145 (model says 60-70 -> 2x mismatch,
// measure before redesigning).
// Pre-committed: t_h0<=60 -> h0 at HBM floor, polish/declare; 65-90 &
// VALU>50% -> ballot-compaction; 65-90 & both low -> latency fix; >90 ->
// guard-branch overhead -> ballot-compaction.
// ============================================================================

#define N_NODES 20000
#define S_COLS  4096
#define E_EDGES 640000
#define D_DIM   256

typedef unsigned short bf16_t;
typedef __attribute__((ext_vector_type(8))) short short8;
typedef __attribute__((ext_vector_type(4))) float f32x4;

__device__ __forceinline__ float bf2f(bf16_t u) {
    union { unsigned int i; float f; } v; v.i = ((unsigned int)u) << 16; return v.f;
}
__device__ __forceinline__ bf16_t f2bf(float x) {   // round-to-nearest-even
    union { float f; unsigned int i; } v; v.f = x;
    unsigned int r = v.i + 0x7FFF + ((v.i >> 16) & 1);
    return (bf16_t)(r >> 16);
}
__device__ __forceinline__ float lo_bf(unsigned int u) {
    union { unsigned int i; float f; } v; v.i = u << 16; return v.f;
}
__device__ __forceinline__ float hi_bf(unsigned int u) {
    union { unsigned int i; float f; } v; v.i = u & 0xFFFF0000u; return v.f;
}
__device__ __forceinline__ unsigned int pack_bf(float a, float b) {
    return (unsigned int)f2bf(a) | ((unsigned int)f2bf(b) << 16);
}

// ---------------------------------------------------------------------------
// MEGA front-end (r7, kept): blocks [0,5000) h0 wave-per-row x4,
// [5000,7500) edge count, [7500,7756) wsplit.
// ---------------------------------------------------------------------------
__global__ void __launch_bounds__(256, 4)
mega_kernel(const float* __restrict__ init_m,
            const float* __restrict__ w1, const float* __restrict__ b1,
            const float* __restrict__ w2, const float* __restrict__ b2,
            bf16_t* __restrict__ h,
            const int* __restrict__ eidx, int* __restrict__ cnt,
            const float* __restrict__ W,
            bf16_t* __restrict__ Wt_hi, bf16_t* __restrict__ Wt_lo) {
    int b = blockIdx.x;
    int t = threadIdx.x;

    if (b >= 5000) {
        int bb = b - 5000;
        if (bb < 2500) {                       // ---- edge count ----
            int e = bb * 256 + t;
            atomicAdd(&cnt[eidx[E_EDGES + e]], 1);
        } else {                               // ---- wsplit ----
            int k = bb - 2500;                 // 0..255
            float w = W[k * D_DIM + t];
            bf16_t hi = f2bf(w);
            bf16_t lo = f2bf(w - bf2f(hi));
            Wt_hi[t * D_DIM + k] = hi;
            Wt_lo[t * D_DIM + k] = lo;
        }
        return;
    }

    // ---- h0: wave-per-row ----
    __shared__ float w2s[16][256];             // 16 KB
#pragma unroll
    for (int k = 0; k < 16; ++k) w2s[k][t] = w2[k * D_DIM + t];
    __syncthreads();                           // only barrier in this branch

    int wave = t >> 6, lane = t & 63;
    int row  = b * 4 + wave;                   // 5000*4 = 20000 rows exactly

    float lw1[16], lb1[16];
#pragma unroll
    for (int k = 0; k < 16; ++k) { lw1[k] = w1[k]; lb1[k] = b1[k]; }

    const float4* rowp = (const float4*)(init_m + (size_t)row * S_COLS);
    float f[16] = {};
    float cn = 0.f;

#define PROC_COMP(val, jb)                                            \
    if ((val) != 0.f) {                                               \
        float jf = (float)(jb);                                       \
        _Pragma("unroll")                                             \
        for (int k = 0; k < 16; ++k)                                  \
            f[k] += fmaxf(jf * lw1[k] + lb1[k], 0.f);                 \
        cn += 1.f;                                                    \
    }

#pragma unroll 4
    for (int v = 0; v < 16; ++v) {
        float4 x = rowp[v * 64 + lane];
        int jb = (v * 64 + lane) * 4;
        PROC_COMP(x.x, jb)
        PROC_COMP(x.y, jb + 1)
        PROC_COMP(x.z, jb + 2)
        PROC_COMP(x.w, jb + 3)
    }
#undef PROC_COMP

    // 64-lane butterfly: every lane ends with the full-row sums
#pragma unroll
    for (int off = 32; off > 0; off >>= 1) {
#pragma unroll
        for (int k = 0; k < 16; ++k) f[k] += __shfl_xor(f[k], off, 64);
        cn += __shfl_xor(cn, off, 64);
    }

    // epilogue: lane -> cols [4*lane, 4*lane+4)
    float4 b2v = *(const float4*)(b2 + 4 * lane);
    float o0 = cn * b2v.x, o1 = cn * b2v.y, o2 = cn * b2v.z, o3 = cn * b2v.w;
#pragma unroll
    for (int k = 0; k < 16; ++k) {
        float4 wv = *(const float4*)(&w2s[k][4 * lane]);   // contiguous b128
        o0 += f[k] * wv.x;  o1 += f[k] * wv.y;
        o2 += f[k] * wv.z;  o3 += f[k] * wv.w;
    }
    float inv = 1.f / fmaxf(cn, 1.f);
    uint2 o;
    o.x = pack_bf(o0 * inv, o1 * inv);
    o.y = pack_bf(o2 * inv, o3 * inv);
    *(uint2*)(h + (size_t)row * D_DIM + 4 * lane) = o;
}

// ---------------------------------------------------------------------------
// DIAGNOSTIC: current wave-per-row h0 x6 reps over shifted rows, dump sink.
// t_h0 = dur/6. Reads 6 x 327MB (shift is bijective mod 20000 per rep).
// ---------------------------------------------------------------------------
__global__ void __launch_bounds__(256, 4)
h0diag2_kernel(const float* __restrict__ init_m,
               const float* __restrict__ w1, const float* __restrict__ b1,
               const float* __restrict__ w2, const float* __restrict__ b2,
               bf16_t* __restrict__ dump) {
    __shared__ float w2s[16][256];
    int t = threadIdx.x;
#pragma unroll
    for (int k = 0; k < 16; ++k) w2s[k][t] = w2[k * D_DIM + t];
    __syncthreads();

    int wave = t >> 6, lane = t & 63;
    int row0 = blockIdx.x * 4 + wave;

    float lw1[16], lb1[16];
#pragma unroll
    for (int k = 0; k < 16; ++k) { lw1[k] = w1[k]; lb1[k] = b1[k]; }

    for (int rep = 0; rep < 6; ++rep) {
        int row = row0 + rep * 3334;
        if (row >= N_NODES) row -= N_NODES;    // max 36669 -> one subtract ok

        const float4* rowp = (const float4*)(init_m + (size_t)row * S_COLS);
        float f[16] = {};
        float cn = 0.f;

#define PROC_COMP(val, jb)                                            \
    if ((val) != 0.f) {                                               \
        float jf = (float)(jb);                                       \
        _Pragma("unroll")                                             \
        for (int k = 0; k < 16; ++k)                                  \
            f[k] += fmaxf(jf * lw1[k] + lb1[k], 0.f);                 \
        cn += 1.f;                                                    \
    }

#pragma unroll 4
        for (int v = 0; v < 16; ++v) {
            float4 x = rowp[v * 64 + lane];
            int jb = (v * 64 + lane) * 4;
            PROC_COMP(x.x, jb)
            PROC_COMP(x.y, jb + 1)
            PROC_COMP(x.z, jb + 2)
            PROC_COMP(x.w, jb + 3)
        }
#undef PROC_COMP

#pragma unroll
        for (int off = 32; off > 0; off >>= 1) {
#pragma unroll
            for (int k = 0; k < 16; ++k) f[k] += __shfl_xor(f[k], off, 64);
            cn += __shfl_xor(cn, off, 64);
        }

        float4 b2v = *(const float4*)(b2 + 4 * lane);
        float o0 = cn * b2v.x, o1 = cn * b2v.y, o2 = cn * b2v.z, o3 = cn * b2v.w;
#pragma unroll
        for (int k = 0; k < 16; ++k) {
            float4 wv = *(const float4*)(&w2s[k][4 * lane]);
            o0 += f[k] * wv.x;  o1 += f[k] * wv.y;
            o2 += f[k] * wv.z;  o3 += f[k] * wv.w;
        }
        float inv = 1.f / fmaxf(cn, 1.f);
        uint2 o;
        o.x = pack_bf(o0 * inv, o1 * inv);
        o.y = pack_bf(o2 * inv, o3 * inv);
        *(uint2*)(dump + (size_t)row * D_DIM + 4 * lane) = o;
    }
}

// ---------------------------------------------------------------------------
// CSC build: scan + fill (UNCHANGED)
// ---------------------------------------------------------------------------
__global__ void scan_kernel(const int* __restrict__ cnt, int* __restrict__ offs,
                            int* __restrict__ cur) {
    __shared__ int sdata[1024];
    int t = threadIdx.x;
    int base = t * 20;
    int vals[20];
    int local = 0;
#pragma unroll
    for (int k = 0; k < 20; ++k) {
        int idx = base + k;
        int v = (idx < N_NODES) ? cnt[idx] : 0;
        vals[k] = local;
        local += v;
    }
    sdata[t] = local;
    __syncthreads();
    for (int off = 1; off < 1024; off <<= 1) {
        int v = (t >= off) ? sdata[t - off] : 0;
        __syncthreads();
        sdata[t] += v;
        __syncthreads();
    }
    int prefix = (t == 0) ? 0 : sdata[t - 1];
#pragma unroll
    for (int k = 0; k < 20; ++k) {
        int idx = base + k;
        if (idx < N_NODES) {
            int o = prefix + vals[k];
            offs[idx] = o;
            cur[idx]  = o;
        }
    }
    if (t == 1023) offs[N_NODES] = sdata[1023];
}

__global__ void fill_kernel(const int* __restrict__ eidx, const float* __restrict__ attr,
                            int* __restrict__ cur, int* __restrict__ src_s,
                            float* __restrict__ attr_s) {
    int e = blockIdx.x * 256 + threadIdx.x;
    if (e < E_EDGES) {
        int r = eidx[e];
        int c = eidx[E_EDGES + e];
        int pos = atomicAdd(&cur[c], 1);
        src_s[pos]  = r;
        attr_s[pos] = attr[e];
    }
}

// ---------------------------------------------------------------------------
// Gather (UNCHANGED): g[c] = sum_e h[src[e]] * attr[e]
// ---------------------------------------------------------------------------
__global__ void gather_kernel(const bf16_t* __restrict__ h,
                              const int* __restrict__ offs,
                              const int* __restrict__ src_s,
                              const float* __restrict__ attr_s,
                              bf16_t* __restrict__ g) {
    int wid  = (blockIdx.x * blockDim.x + threadIdx.x) >> 6;
    int lane = threadIdx.x & 63;
    if (wid >= N_NODES) return;
    int half = lane >> 5;
    int l32  = lane & 31;
    int e0 = offs[wid], e1 = offs[wid + 1];

    float acc[8] = {};
    for (int base = e0; base < e1; base += 64) {
        int n = e1 - base; if (n > 64) n = 64;
        int   r_l = 0; float a_l = 0.f;
        if (lane < n) { r_l = src_s[base + lane]; a_l = attr_s[base + lane]; }
        int nn = (n + 15) & ~15;            // pad to 8 pair-iterations
        for (int q = 0; q < nn; q += 16) {
#pragma unroll
            for (int u = 0; u < 8; ++u) {
                int   sl = q + 2 * u + half;
                int   r  = __shfl(r_l, sl, 64);
                float a  = __shfl(a_l, sl, 64);
                uint4 v  = ((const uint4*)(h + (size_t)r * D_DIM))[l32];
                acc[0] += lo_bf(v.x) * a;  acc[1] += hi_bf(v.x) * a;
                acc[2] += lo_bf(v.y) * a;  acc[3] += hi_bf(v.y) * a;
                acc[4] += lo_bf(v.z) * a;  acc[5] += hi_bf(v.z) * a;
                acc[6] += lo_bf(v.w) * a;  acc[7] += hi_bf(v.w) * a;
            }
        }
    }
#pragma unroll
    for (int i = 0; i < 8; ++i) acc[i] += __shfl_xor(acc[i], 32, 64);

    if (half == 0) {
        uint4 o;
        o.x = pack_bf(acc[0], acc[1]);
        o.y = pack_bf(acc[2], acc[3]);
        o.z = pack_bf(acc[4], acc[5]);
        o.w = pack_bf(acc[6], acc[7]);
        ((uint4*)(g + (size_t)wid * D_DIM))[l32] = o;
    }
}

// ---------------------------------------------------------------------------
// GEMM v4 (r10, kept): h' = relu(g @ W), persistent-B, dual-M-tile waves.
// ---------------------------------------------------------------------------
__global__ void __launch_bounds__(256, 2)
gemm_relu_kernel(const bf16_t* __restrict__ g,
                 const bf16_t* __restrict__ Wt_hi,
                 const bf16_t* __restrict__ Wt_lo,
                 bf16_t* __restrict__ hdst, float* __restrict__ fdst) {
    __shared__ bf16_t Bs[64][512];           // 64 KB: [n][k: 0..255 hi | 256..511 lo]
    int tid  = threadIdx.x;
    int w    = tid >> 6;
    int lane = tid & 63;
    int quad = lane >> 4;
    int id16 = lane & 15;

    int d    = blockIdx.x;                   // 0..627
    int xcd  = d & 7;
    int base = (xcd < 4) ? xcd * 79 : 316 + (xcd - 4) * 78;
    int wg   = base + (d >> 3);
    int bx   = wg >> 2;                      // 0..156 row-panel
    int by   = wg & 3;                       // 0..3   col-slab
    int bn   = by * 64;
    int bm0  = bx * 128;                     // up to 20096: gbuf pad absorbs

    char* bs = (char*)Bs;

    {
        int tn0 = tid >> 4;
        int ts0 = tid & 15;
#pragma unroll
        for (int it = 0; it < 16; ++it) {
            int n   = tn0 + (it & 3) * 16;
            int seg = ts0 + (it >> 2) * 16;
            const bf16_t* src = (seg < 32 ? Wt_hi : Wt_lo)
                              + (size_t)(bn + n) * D_DIM + (seg & 31) * 8;
            unsigned off = (unsigned)(n * 1024 + seg * 16) ^ (unsigned)((n & 7) << 4);
            *(uint4*)(bs + off) = *(const uint4*)src;
        }
    }

    int r0 = bm0 + w * 32;
    short8 areg[2][8];
#pragma unroll
    for (int j = 0; j < 2; ++j) {
        const bf16_t* arow = g + (size_t)(r0 + j * 16 + id16) * D_DIM;
#pragma unroll
        for (int i = 0; i < 8; ++i)
            areg[j][i] = *(const short8*)(arow + i * 32 + quad * 8);
    }

    __syncthreads();                         // the only barrier

    unsigned swz   = (unsigned)((id16 & 7) << 4);
    unsigned nbase = (unsigned)(id16 * 1024);

    f32x4 acc[2][4];
#pragma unroll
    for (int j = 0; j < 2; ++j)
#pragma unroll
        for (int nt = 0; nt < 4; ++nt) acc[j][nt] = (f32x4){0.f, 0.f, 0.f, 0.f};

#pragma unroll
    for (int ks = 0; ks < 8; ++ks) {
        unsigned kb = ((unsigned)(ks * 64 + quad * 16)) ^ swz;
#pragma unroll
        for (int nt = 0; nt < 4; ++nt) {
            unsigned off = (unsigned)(nt * 16384) + nbase + kb;
            short8 bh = *(const short8*)(bs + off);         // hi plane
            short8 bl = *(const short8*)(bs + off + 512);   // lo plane
            acc[0][nt] = __builtin_amdgcn_mfma_f32_16x16x32_bf16(areg[0][ks], bh, acc[0][nt], 0, 0, 0);
            acc[0][nt] = __builtin_amdgcn_mfma_f32_16x16x32_bf16(areg[0][ks], bl, acc[0][nt], 0, 0, 0);
            acc[1][nt] = __builtin_amdgcn_mfma_f32_16x16x32_bf16(areg[1][ks], bh, acc[1][nt], 0, 0, 0);
            acc[1][nt] = __builtin_amdgcn_mfma_f32_16x16x32_bf16(areg[1][ks], bl, acc[1][nt], 0, 0, 0);
        }
    }

#pragma unroll
    for (int j = 0; j < 2; ++j) {
#pragma unroll
        for (int nt = 0; nt < 4; ++nt) {
#pragma unroll
            for (int r = 0; r < 4; ++r) {
                int m = r0 + j * 16 + quad * 4 + r;
                if (m < N_NODES) {
                    int n = bn + nt * 16 + id16;
                    float v = fmaxf(acc[j][nt][r], 0.f);
                    if (hdst) hdst[(size_t)m * D_DIM + n] = f2bf(v);
                    else      fdst[(size_t)m * D_DIM + n] = v;
                }
            }
        }
    }
}

extern "C" void kernel_launch(void* const* d_in, const int* in_sizes, int n_in,
                              void* d_out, int out_size, void* d_ws, size_t ws_size,
                              hipStream_t stream) {
    const float* init_m = (const float*)d_in[0];
    const int*   eidx   = (const int*)  d_in[1];
    const float* attr   = (const float*)d_in[2];
    const float* w1     = (const float*)d_in[3];
    const float* b1     = (const float*)d_in[4];
    const float* w2     = (const float*)d_in[5];
    const float* b2     = (const float*)d_in[6];
    const float* Wm     = (const float*)d_in[7];
    float* out = (float*)d_out;

    char* ws = (char*)d_ws;
    bf16_t* hbuf   = (bf16_t*)ws;                        // 10,240,000
    bf16_t* gbuf   = (bf16_t*)(ws + 10240000);           // 10,289,152 (incl 96 pad rows)
    int*    cnt    = (int*)   (ws + 20529152);
    int*    offs   = (int*)   (ws + 20609152);
    int*    cur    = (int*)   (ws + 20689408);
    int*    src_s  = (int*)   (ws + 20769408);
    float*  attr_s = (float*) (ws + 23329408);
    bf16_t* Wt_hi  = (bf16_t*)(ws + 25889408);
    bf16_t* Wt_lo  = (bf16_t*)(ws + 26020480);
    bf16_t* gdump  = (bf16_t*)(ws + 26151552);           // 10,240,000 diagnostic sink

    // single memset covers gbuf pad rows + cnt
    hipMemsetAsync(ws + 20480000, 0, 129152, stream);

    // front-end: h0 (wave-per-row) + edge-count + wsplit in one dispatch
    mega_kernel<<<5000 + 2500 + 256, 256, 0, stream>>>(
        init_m, w1, b1, w2, b2, hbuf, eidx, cnt, Wm, Wt_hi, Wt_lo);

    // DIAGNOSTIC: current h0 x6, surfaces in top-5 with own counters.
    h0diag2_kernel<<<5000, 256, 0, stream>>>(init_m, w1, b1, w2, b2, gdump);

    scan_kernel<<<1, 1024, 0, stream>>>(cnt, offs, cur);
    fill_kernel<<<(E_EDGES + 255) / 256, 256, 0, stream>>>(eidx, attr, cur, src_s, attr_s);

    // 3x GCN layer: g = gather(h); h' = relu(g @ W)
    dim3 ggrid((N_NODES * 64 + 255) / 256);
    for (int it = 0; it < 3; ++it) {
        gather_kernel<<<ggrid, 256, 0, stream>>>(hbuf, offs, src_s, attr_s, gbuf);
        if (it == 2)
            gemm_relu_kernel<<<628, 256, 0, stream>>>(gbuf, Wt_hi, Wt_lo,
                                                      (bf16_t*)nullptr, out);
        else
            gemm_relu_kernel<<<628, 256, 0, stream>>>(gbuf, Wt_hi, Wt_lo,
                                                      hbuf, (float*)nullptr);
    }
}

// Round 12
// 684.668 us; speedup vs baseline: 1.9401x; 1.9401x over previous
//
#include <hip/hip_runtime.h>

// ============================================================================
// ROUND 12: h0 as MFMA mask-GEMM. r11 measured: t_h0=109us, VALU 91.5%, HBM
// 20% -> guarded-FMA on 98%-zero data (72% of component-slots taken, ~1.8/64
// lanes active). Identity: fsum = mask @ P, P[j,f]=relu(j*w1[f]+b1[f])
// (row-independent, precomputed hi/lo bf16 by pphi_kernel); cnt = mask @ 1
// (constant ones B-tile, exact). h0 block = 16 rows, 4 waves x K=1024; per
// k-step: 2 A-float4 loads -> 1.0/0.0 bf16 frag (cmp+sel, ~20 VALU), 2 B
// loads (Pt hi/lo, L2-resident), 3 MFMA. LDS reduce + w2 projection.
// Prediction: h0 -> 60-70us (HBM floor), total 694.3 -> ~645-660.
// Everything else byte-identical to r10 (gather/gemm/scan/fill).
// ============================================================================

#define N_NODES 20000
#define S_COLS  4096
#define E_EDGES 640000
#define D_DIM   256

typedef unsigned short bf16_t;
typedef __attribute__((ext_vector_type(8))) short short8;
typedef __attribute__((ext_vector_type(4))) float f32x4;

__device__ __forceinline__ float bf2f(bf16_t u) {
    union { unsigned int i; float f; } v; v.i = ((unsigned int)u) << 16; return v.f;
}
__device__ __forceinline__ bf16_t f2bf(float x) {   // round-to-nearest-even
    union { float f; unsigned int i; } v; v.f = x;
    unsigned int r = v.i + 0x7FFF + ((v.i >> 16) & 1);
    return (bf16_t)(r >> 16);
}
__device__ __forceinline__ float lo_bf(unsigned int u) {
    union { unsigned int i; float f; } v; v.i = u << 16; return v.f;
}
__device__ __forceinline__ float hi_bf(unsigned int u) {
    union { unsigned int i; float f; } v; v.i = u & 0xFFFF0000u; return v.f;
}
__device__ __forceinline__ unsigned int pack_bf(float a, float b) {
    return (unsigned int)f2bf(a) | ((unsigned int)f2bf(b) << 16);
}

// ---------------------------------------------------------------------------
// P precompute: Pt_hi/Pt_lo [16][4096] bf16, phi(j)[f] = relu(j*w1[f]+b1[f]).
// Runs before mega (stream-ordered). Coalesced u16 stores (lanes vary j).
// ---------------------------------------------------------------------------
__global__ void pphi_kernel(const float* __restrict__ w1, const float* __restrict__ b1,
                            bf16_t* __restrict__ Pt_hi, bf16_t* __restrict__ Pt_lo) {
    int j = blockIdx.x * 256 + threadIdx.x;        // 0..4095
    float jf = (float)j;
#pragma unroll
    for (int f = 0; f < 16; ++f) {
        float phi = fmaxf(jf * w1[f] + b1[f], 0.f);
        bf16_t hi = f2bf(phi);
        bf16_t lo = f2bf(phi - bf2f(hi));
        Pt_hi[f * S_COLS + j] = hi;
        Pt_lo[f * S_COLS + j] = lo;
    }
}

// ---------------------------------------------------------------------------
// MEGA front-end: blocks [0,1250) h0 mask-MFMA (16 rows each),
// [1250,3750) edge count, [3750,4006) wsplit.
// ---------------------------------------------------------------------------
__global__ void __launch_bounds__(256, 4)
mega_kernel(const float* __restrict__ init_m,
            const float* __restrict__ w2, const float* __restrict__ b2,
            const bf16_t* __restrict__ Pt_hi, const bf16_t* __restrict__ Pt_lo,
            bf16_t* __restrict__ h,
            const int* __restrict__ eidx, int* __restrict__ cnt,
            const float* __restrict__ W,
            bf16_t* __restrict__ Wt_hi, bf16_t* __restrict__ Wt_lo) {
    int b = blockIdx.x;
    int t = threadIdx.x;

    if (b >= 1250) {
        int bb = b - 1250;
        if (bb < 2500) {                       // ---- edge count ----
            int e = bb * 256 + t;
            atomicAdd(&cnt[eidx[E_EDGES + e]], 1);
        } else {                               // ---- wsplit ----
            int k = bb - 2500;                 // 0..255
            float w = W[k * D_DIM + t];
            bf16_t hi = f2bf(w);
            bf16_t lo = f2bf(w - bf2f(hi));
            Wt_hi[t * D_DIM + k] = hi;
            Wt_lo[t * D_DIM + k] = lo;
        }
        return;
    }

    // ---- h0 mask-MFMA: F = mask @ [P_hi;P_lo], cnt = mask @ ones ----
    __shared__ float w2s[16][256];             // 16 KB
    __shared__ float Fred[4][16][16];          // 4 KB
    __shared__ float Cred[4][16];              // 256 B

#pragma unroll
    for (int k = 0; k < 16; ++k) w2s[k][t] = w2[k * D_DIM + t];

    int wave = t >> 6, lane = t & 63;
    int quad = lane >> 4, id16 = lane & 15;
    int r0 = b * 16;                           // 1250*16 = 20000 exactly

    const float*  arow = init_m + (size_t)(r0 + id16) * S_COLS + wave * 1024 + quad * 8;
    const bf16_t* bph  = Pt_hi + id16 * S_COLS + wave * 1024 + quad * 8;
    const bf16_t* bpl  = Pt_lo + id16 * S_COLS + wave * 1024 + quad * 8;

    // ones B-tile: col 0 = 1.0 for all k -> lanes with id16==0 hold bf16(1.0)x8
    short8 bones;
    short ov = (id16 == 0) ? (short)0x3F80 : (short)0;
#pragma unroll
    for (int i = 0; i < 8; ++i) bones[i] = ov;

    f32x4 accF = (f32x4){0.f, 0.f, 0.f, 0.f};
    f32x4 accC = (f32x4){0.f, 0.f, 0.f, 0.f};

    const short M1 = (short)0x3F80;            // bf16 1.0
#pragma unroll 4
    for (int s = 0; s < 32; ++s) {
        float4 x0 = *(const float4*)(arow + s * 32);
        float4 x1 = *(const float4*)(arow + s * 32 + 4);
        short8 bh = *(const short8*)(bph + s * 32);
        short8 bl = *(const short8*)(bpl + s * 32);
        short8 a;
        a[0] = (x0.x != 0.f) ? M1 : (short)0;
        a[1] = (x0.y != 0.f) ? M1 : (short)0;
        a[2] = (x0.z != 0.f) ? M1 : (short)0;
        a[3] = (x0.w != 0.f) ? M1 : (short)0;
        a[4] = (x1.x != 0.f) ? M1 : (short)0;
        a[5] = (x1.y != 0.f) ? M1 : (short)0;
        a[6] = (x1.z != 0.f) ? M1 : (short)0;
        a[7] = (x1.w != 0.f) ? M1 : (short)0;
        accF = __builtin_amdgcn_mfma_f32_16x16x32_bf16(a, bh, accF, 0, 0, 0);
        accF = __builtin_amdgcn_mfma_f32_16x16x32_bf16(a, bl, accF, 0, 0, 0);
        accC = __builtin_amdgcn_mfma_f32_16x16x32_bf16(a, bones, accC, 0, 0, 0);
    }

    // write partials (C/D layout: col=id16, row=quad*4+r)
#pragma unroll
    for (int r = 0; r < 4; ++r)
        Fred[wave][quad * 4 + r][id16] = accF[r];
    if (id16 == 0) {
#pragma unroll
        for (int r = 0; r < 4; ++r)
            Cred[wave][quad * 4 + r] = accC[r];
    }
    __syncthreads();

    // reduce + project: thread t -> row = t>>4, col-group cg = t&15
    int row = t >> 4, cg = t & 15;
    float Frow[16];
#pragma unroll
    for (int f = 0; f < 16; ++f)
        Frow[f] = Fred[0][row][f] + Fred[1][row][f] + Fred[2][row][f] + Fred[3][row][f];
    float cn = Cred[0][row] + Cred[1][row] + Cred[2][row] + Cred[3][row];
    float inv = 1.f / fmaxf(cn, 1.f);

    int c0 = cg * 16;
    float o[16];
#pragma unroll
    for (int jj = 0; jj < 4; ++jj) {
        float4 bv = *(const float4*)(b2 + c0 + jj * 4);
        o[jj * 4 + 0] = cn * bv.x;  o[jj * 4 + 1] = cn * bv.y;
        o[jj * 4 + 2] = cn * bv.z;  o[jj * 4 + 3] = cn * bv.w;
    }
#pragma unroll
    for (int f = 0; f < 16; ++f) {
        float fv = Frow[f];
#pragma unroll
        for (int jj = 0; jj < 16; ++jj)
            o[jj] += fv * w2s[f][c0 + jj];
    }
    uint4 p0, p1;
    p0.x = pack_bf(o[0] * inv,  o[1] * inv);
    p0.y = pack_bf(o[2] * inv,  o[3] * inv);
    p0.z = pack_bf(o[4] * inv,  o[5] * inv);
    p0.w = pack_bf(o[6] * inv,  o[7] * inv);
    p1.x = pack_bf(o[8] * inv,  o[9] * inv);
    p1.y = pack_bf(o[10] * inv, o[11] * inv);
    p1.z = pack_bf(o[12] * inv, o[13] * inv);
    p1.w = pack_bf(o[14] * inv, o[15] * inv);
    uint4* dst = (uint4*)(h + (size_t)(r0 + row) * D_DIM + c0);
    dst[0] = p0;
    dst[1] = p1;
}

// ---------------------------------------------------------------------------
// CSC build: scan + fill (UNCHANGED)
// ---------------------------------------------------------------------------
__global__ void scan_kernel(const int* __restrict__ cnt, int* __restrict__ offs,
                            int* __restrict__ cur) {
    __shared__ int sdata[1024];
    int t = threadIdx.x;
    int base = t * 20;
    int vals[20];
    int local = 0;
#pragma unroll
    for (int k = 0; k < 20; ++k) {
        int idx = base + k;
        int v = (idx < N_NODES) ? cnt[idx] : 0;
        vals[k] = local;
        local += v;
    }
    sdata[t] = local;
    __syncthreads();
    for (int off = 1; off < 1024; off <<= 1) {
        int v = (t >= off) ? sdata[t - off] : 0;
        __syncthreads();
        sdata[t] += v;
        __syncthreads();
    }
    int prefix = (t == 0) ? 0 : sdata[t - 1];
#pragma unroll
    for (int k = 0; k < 20; ++k) {
        int idx = base + k;
        if (idx < N_NODES) {
            int o = prefix + vals[k];
            offs[idx] = o;
            cur[idx]  = o;
        }
    }
    if (t == 1023) offs[N_NODES] = sdata[1023];
}

__global__ void fill_kernel(const int* __restrict__ eidx, const float* __restrict__ attr,
                            int* __restrict__ cur, int* __restrict__ src_s,
                            float* __restrict__ attr_s) {
    int e = blockIdx.x * 256 + threadIdx.x;
    if (e < E_EDGES) {
        int r = eidx[e];
        int c = eidx[E_EDGES + e];
        int pos = atomicAdd(&cur[c], 1);
        src_s[pos]  = r;
        attr_s[pos] = attr[e];
    }
}

// ---------------------------------------------------------------------------
// Gather (UNCHANGED): g[c] = sum_e h[src[e]] * attr[e]
// ---------------------------------------------------------------------------
__global__ void gather_kernel(const bf16_t* __restrict__ h,
                              const int* __restrict__ offs,
                              const int* __restrict__ src_s,
                              const float* __restrict__ attr_s,
                              bf16_t* __restrict__ g) {
    int wid  = (blockIdx.x * blockDim.x + threadIdx.x) >> 6;
    int lane = threadIdx.x & 63;
    if (wid >= N_NODES) return;
    int half = lane >> 5;
    int l32  = lane & 31;
    int e0 = offs[wid], e1 = offs[wid + 1];

    float acc[8] = {};
    for (int base = e0; base < e1; base += 64) {
        int n = e1 - base; if (n > 64) n = 64;
        int   r_l = 0; float a_l = 0.f;
        if (lane < n) { r_l = src_s[base + lane]; a_l = attr_s[base + lane]; }
        int nn = (n + 15) & ~15;            // pad to 8 pair-iterations
        for (int q = 0; q < nn; q += 16) {
#pragma unroll
            for (int u = 0; u < 8; ++u) {
                int   sl = q + 2 * u + half;
                int   r  = __shfl(r_l, sl, 64);
                float a  = __shfl(a_l, sl, 64);
                uint4 v  = ((const uint4*)(h + (size_t)r * D_DIM))[l32];
                acc[0] += lo_bf(v.x) * a;  acc[1] += hi_bf(v.x) * a;
                acc[2] += lo_bf(v.y) * a;  acc[3] += hi_bf(v.y) * a;
                acc[4] += lo_bf(v.z) * a;  acc[5] += hi_bf(v.z) * a;
                acc[6] += lo_bf(v.w) * a;  acc[7] += hi_bf(v.w) * a;
            }
        }
    }
#pragma unroll
    for (int i = 0; i < 8; ++i) acc[i] += __shfl_xor(acc[i], 32, 64);

    if (half == 0) {
        uint4 o;
        o.x = pack_bf(acc[0], acc[1]);
        o.y = pack_bf(acc[2], acc[3]);
        o.z = pack_bf(acc[4], acc[5]);
        o.w = pack_bf(acc[6], acc[7]);
        ((uint4*)(g + (size_t)wid * D_DIM))[l32] = o;
    }
}

// ---------------------------------------------------------------------------
// GEMM v4 (r10, kept): h' = relu(g @ W), persistent-B, dual-M-tile waves.
// ---------------------------------------------------------------------------
__global__ void __launch_bounds__(256, 2)
gemm_relu_kernel(const bf16_t* __restrict__ g,
                 const bf16_t* __restrict__ Wt_hi,
                 const bf16_t* __restrict__ Wt_lo,
                 bf16_t* __restrict__ hdst, float* __restrict__ fdst) {
    __shared__ bf16_t Bs[64][512];           // 64 KB: [n][k: 0..255 hi | 256..511 lo]
    int tid  = threadIdx.x;
    int w    = tid >> 6;
    int lane = tid & 63;
    int quad = lane >> 4;
    int id16 = lane & 15;

    int d    = blockIdx.x;                   // 0..627
    int xcd  = d & 7;
    int base = (xcd < 4) ? xcd * 79 : 316 + (xcd - 4) * 78;
    int wg   = base + (d >> 3);
    int bx   = wg >> 2;                      // 0..156 row-panel
    int by   = wg & 3;                       // 0..3   col-slab
    int bn   = by * 64;
    int bm0  = bx * 128;                     // up to 20096: gbuf pad absorbs

    char* bs = (char*)Bs;

    {
        int tn0 = tid >> 4;
        int ts0 = tid & 15;
#pragma unroll
        for (int it = 0; it < 16; ++it) {
            int n   = tn0 + (it & 3) * 16;
            int seg = ts0 + (it >> 2) * 16;
            const bf16_t* src = (seg < 32 ? Wt_hi : Wt_lo)
                              + (size_t)(bn + n) * D_DIM + (seg & 31) * 8;
            unsigned off = (unsigned)(n * 1024 + seg * 16) ^ (unsigned)((n & 7) << 4);
            *(uint4*)(bs + off) = *(const uint4*)src;
        }
    }

    int r0 = bm0 + w * 32;
    short8 areg[2][8];
#pragma unroll
    for (int j = 0; j < 2; ++j) {
        const bf16_t* arow = g + (size_t)(r0 + j * 16 + id16) * D_DIM;
#pragma unroll
        for (int i = 0; i < 8; ++i)
            areg[j][i] = *(const short8*)(arow + i * 32 + quad * 8);
    }

    __syncthreads();                         // the only barrier

    unsigned swz   = (unsigned)((id16 & 7) << 4);
    unsigned nbase = (unsigned)(id16 * 1024);

    f32x4 acc[2][4];
#pragma unroll
    for (int j = 0; j < 2; ++j)
#pragma unroll
        for (int nt = 0; nt < 4; ++nt) acc[j][nt] = (f32x4){0.f, 0.f, 0.f, 0.f};

#pragma unroll
    for (int ks = 0; ks < 8; ++ks) {
        unsigned kb = ((unsigned)(ks * 64 + quad * 16)) ^ swz;
#pragma unroll
        for (int nt = 0; nt < 4; ++nt) {
            unsigned off = (unsigned)(nt * 16384) + nbase + kb;
            short8 bh = *(const short8*)(bs + off);         // hi plane
            short8 bl = *(const short8*)(bs + off + 512);   // lo plane
            acc[0][nt] = __builtin_amdgcn_mfma_f32_16x16x32_bf16(areg[0][ks], bh, acc[0][nt], 0, 0, 0);
            acc[0][nt] = __builtin_amdgcn_mfma_f32_16x16x32_bf16(areg[0][ks], bl, acc[0][nt], 0, 0, 0);
            acc[1][nt] = __builtin_amdgcn_mfma_f32_16x16x32_bf16(areg[1][ks], bh, acc[1][nt], 0, 0, 0);
            acc[1][nt] = __builtin_amdgcn_mfma_f32_16x16x32_bf16(areg[1][ks], bl, acc[1][nt], 0, 0, 0);
        }
    }

#pragma unroll
    for (int j = 0; j < 2; ++j) {
#pragma unroll
        for (int nt = 0; nt < 4; ++nt) {
#pragma unroll
            for (int r = 0; r < 4; ++r) {
                int m = r0 + j * 16 + quad * 4 + r;
                if (m < N_NODES) {
                    int n = bn + nt * 16 + id16;
                    float v = fmaxf(acc[j][nt][r], 0.f);
                    if (hdst) hdst[(size_t)m * D_DIM + n] = f2bf(v);
                    else      fdst[(size_t)m * D_DIM + n] = v;
                }
            }
        }
    }
}

extern "C" void kernel_launch(void* const* d_in, const int* in_sizes, int n_in,
                              void* d_out, int out_size, void* d_ws, size_t ws_size,
                              hipStream_t stream) {
    const float* init_m = (const float*)d_in[0];
    const int*   eidx   = (const int*)  d_in[1];
    const float* attr   = (const float*)d_in[2];
    const float* w1     = (const float*)d_in[3];
    const float* b1     = (const float*)d_in[4];
    const float* w2     = (const float*)d_in[5];
    const float* b2     = (const float*)d_in[6];
    const float* Wm     = (const float*)d_in[7];
    float* out = (float*)d_out;

    char* ws = (char*)d_ws;
    bf16_t* hbuf   = (bf16_t*)ws;                        // 10,240,000
    bf16_t* gbuf   = (bf16_t*)(ws + 10240000);           // 10,289,152 (incl 96 pad rows)
    int*    cnt    = (int*)   (ws + 20529152);
    int*    offs   = (int*)   (ws + 20609152);
    int*    cur    = (int*)   (ws + 20689408);
    int*    src_s  = (int*)   (ws + 20769408);
    float*  attr_s = (float*) (ws + 23329408);
    bf16_t* Wt_hi  = (bf16_t*)(ws + 25889408);
    bf16_t* Wt_lo  = (bf16_t*)(ws + 26020480);
    bf16_t* Pt_hi  = (bf16_t*)(ws + 26151552);           // 131,072
    bf16_t* Pt_lo  = (bf16_t*)(ws + 26282624);           // 131,072

    // single memset covers gbuf pad rows + cnt
    hipMemsetAsync(ws + 20480000, 0, 129152, stream);

    // P table (consumed by mega's h0 branch)
    pphi_kernel<<<16, 256, 0, stream>>>(w1, b1, Pt_hi, Pt_lo);

    // front-end: h0 (mask-MFMA) + edge-count + wsplit in one dispatch
    mega_kernel<<<1250 + 2500 + 256, 256, 0, stream>>>(
        init_m, w2, b2, Pt_hi, Pt_lo, hbuf, eidx, cnt, Wm, Wt_hi, Wt_lo);
    scan_kernel<<<1, 1024, 0, stream>>>(cnt, offs, cur);
    fill_kernel<<<(E_EDGES + 255) / 256, 256, 0, stream>>>(eidx, attr, cur, src_s, attr_s);

    // 3x GCN layer: g = gather(h); h' = relu(g @ W)
    dim3 ggrid((N_NODES * 64 + 255) / 256);
    for (int it = 0; it < 3; ++it) {
        gather_kernel<<<ggrid, 256, 0, stream>>>(hbuf, offs, src_s, attr_s, gbuf);
        if (it == 2)
            gemm_relu_kernel<<<628, 256, 0, stream>>>(gbuf, Wt_hi, Wt_lo,
                                                      (bf16_t*)nullptr, out);
        else
            gemm_relu_kernel<<<628, 256, 0, stream>>>(gbuf, Wt_hi, Wt_lo,
                                                      hbuf, (float*)nullptr);
    }
}

// Round 13
// 652.579 us; speedup vs baseline: 2.0355x; 1.0492x over previous
//
#include <hip/hip_runtime.h>

// ============================================================================
// ROUND 13: scan-free padded CSC. Ledger: fills ~415 (fixed, 82% HBM peak),
// gather 95 (3-variant-invariant floor), gemm ~25 (floor), mega ~65-80
// (HBM floor 52), CSC ~30-45 <- the last slack. Change: capacity-128
// padded CSC (P(deg>128)=1e-40 for Poisson(32)): fill scatters via
// atomicAdd(cur) into c*128+pos; gather uses e0=c<<7, deg=cur[c].
// DELETES scan_kernel + mega's 2500 count blocks; chain mega->fill.
// Prediction: -8..-17us -> ~668-677. Then declare practical roofline.
// ============================================================================

#define N_NODES 20000
#define S_COLS  4096
#define E_EDGES 640000
#define D_DIM   256
#define DEG_CAP 128

typedef unsigned short bf16_t;
typedef __attribute__((ext_vector_type(8))) short short8;
typedef __attribute__((ext_vector_type(4))) float f32x4;

__device__ __forceinline__ float bf2f(bf16_t u) {
    union { unsigned int i; float f; } v; v.i = ((unsigned int)u) << 16; return v.f;
}
__device__ __forceinline__ bf16_t f2bf(float x) {   // round-to-nearest-even
    union { float f; unsigned int i; } v; v.f = x;
    unsigned int r = v.i + 0x7FFF + ((v.i >> 16) & 1);
    return (bf16_t)(r >> 16);
}
__device__ __forceinline__ float lo_bf(unsigned int u) {
    union { unsigned int i; float f; } v; v.i = u << 16; return v.f;
}
__device__ __forceinline__ float hi_bf(unsigned int u) {
    union { unsigned int i; float f; } v; v.i = u & 0xFFFF0000u; return v.f;
}
__device__ __forceinline__ unsigned int pack_bf(float a, float b) {
    return (unsigned int)f2bf(a) | ((unsigned int)f2bf(b) << 16);
}

// ---------------------------------------------------------------------------
// P precompute: Pt_hi/Pt_lo [16][4096] bf16, phi(j)[f] = relu(j*w1[f]+b1[f]).
// ---------------------------------------------------------------------------
__global__ void pphi_kernel(const float* __restrict__ w1, const float* __restrict__ b1,
                            bf16_t* __restrict__ Pt_hi, bf16_t* __restrict__ Pt_lo) {
    int j = blockIdx.x * 256 + threadIdx.x;        // 0..4095
    float jf = (float)j;
#pragma unroll
    for (int f = 0; f < 16; ++f) {
        float phi = fmaxf(jf * w1[f] + b1[f], 0.f);
        bf16_t hi = f2bf(phi);
        bf16_t lo = f2bf(phi - bf2f(hi));
        Pt_hi[f * S_COLS + j] = hi;
        Pt_lo[f * S_COLS + j] = lo;
    }
}

// ---------------------------------------------------------------------------
// MEGA front-end: blocks [0,1250) h0 mask-MFMA (16 rows each),
// [1250,1506) wsplit. (Edge count is gone — padded CSC needs no prefix sum.)
// ---------------------------------------------------------------------------
__global__ void __launch_bounds__(256, 4)
mega_kernel(const float* __restrict__ init_m,
            const float* __restrict__ w2, const float* __restrict__ b2,
            const bf16_t* __restrict__ Pt_hi, const bf16_t* __restrict__ Pt_lo,
            bf16_t* __restrict__ h,
            const float* __restrict__ W,
            bf16_t* __restrict__ Wt_hi, bf16_t* __restrict__ Wt_lo) {
    int b = blockIdx.x;
    int t = threadIdx.x;

    if (b >= 1250) {                           // ---- wsplit ----
        int k = b - 1250;                      // 0..255
        float w = W[k * D_DIM + t];
        bf16_t hi = f2bf(w);
        bf16_t lo = f2bf(w - bf2f(hi));
        Wt_hi[t * D_DIM + k] = hi;
        Wt_lo[t * D_DIM + k] = lo;
        return;
    }

    // ---- h0 mask-MFMA: F = mask @ [P_hi;P_lo], cnt = mask @ ones ----
    __shared__ float w2s[16][256];             // 16 KB
    __shared__ float Fred[4][16][16];          // 4 KB
    __shared__ float Cred[4][16];              // 256 B

#pragma unroll
    for (int k = 0; k < 16; ++k) w2s[k][t] = w2[k * D_DIM + t];

    int wave = t >> 6, lane = t & 63;
    int quad = lane >> 4, id16 = lane & 15;
    int r0 = b * 16;                           // 1250*16 = 20000 exactly

    const float*  arow = init_m + (size_t)(r0 + id16) * S_COLS + wave * 1024 + quad * 8;
    const bf16_t* bph  = Pt_hi + id16 * S_COLS + wave * 1024 + quad * 8;
    const bf16_t* bpl  = Pt_lo + id16 * S_COLS + wave * 1024 + quad * 8;

    short8 bones;
    short ov = (id16 == 0) ? (short)0x3F80 : (short)0;
#pragma unroll
    for (int i = 0; i < 8; ++i) bones[i] = ov;

    f32x4 accF = (f32x4){0.f, 0.f, 0.f, 0.f};
    f32x4 accC = (f32x4){0.f, 0.f, 0.f, 0.f};

    const short M1 = (short)0x3F80;            // bf16 1.0
#pragma unroll 4
    for (int s = 0; s < 32; ++s) {
        float4 x0 = *(const float4*)(arow + s * 32);
        float4 x1 = *(const float4*)(arow + s * 32 + 4);
        short8 bh = *(const short8*)(bph + s * 32);
        short8 bl = *(const short8*)(bpl + s * 32);
        short8 a;
        a[0] = (x0.x != 0.f) ? M1 : (short)0;
        a[1] = (x0.y != 0.f) ? M1 : (short)0;
        a[2] = (x0.z != 0.f) ? M1 : (short)0;
        a[3] = (x0.w != 0.f) ? M1 : (short)0;
        a[4] = (x1.x != 0.f) ? M1 : (short)0;
        a[5] = (x1.y != 0.f) ? M1 : (short)0;
        a[6] = (x1.z != 0.f) ? M1 : (short)0;
        a[7] = (x1.w != 0.f) ? M1 : (short)0;
        accF = __builtin_amdgcn_mfma_f32_16x16x32_bf16(a, bh, accF, 0, 0, 0);
        accF = __builtin_amdgcn_mfma_f32_16x16x32_bf16(a, bl, accF, 0, 0, 0);
        accC = __builtin_amdgcn_mfma_f32_16x16x32_bf16(a, bones, accC, 0, 0, 0);
    }

    // write partials (C/D layout: col=id16, row=quad*4+r)
#pragma unroll
    for (int r = 0; r < 4; ++r)
        Fred[wave][quad * 4 + r][id16] = accF[r];
    if (id16 == 0) {
#pragma unroll
        for (int r = 0; r < 4; ++r)
            Cred[wave][quad * 4 + r] = accC[r];
    }
    __syncthreads();

    // reduce + project: thread t -> row = t>>4, col-group cg = t&15
    int row = t >> 4, cg = t & 15;
    float Frow[16];
#pragma unroll
    for (int f = 0; f < 16; ++f)
        Frow[f] = Fred[0][row][f] + Fred[1][row][f] + Fred[2][row][f] + Fred[3][row][f];
    float cn = Cred[0][row] + Cred[1][row] + Cred[2][row] + Cred[3][row];
    float inv = 1.f / fmaxf(cn, 1.f);

    int c0 = cg * 16;
    float o[16];
#pragma unroll
    for (int jj = 0; jj < 4; ++jj) {
        float4 bv = *(const float4*)(b2 + c0 + jj * 4);
        o[jj * 4 + 0] = cn * bv.x;  o[jj * 4 + 1] = cn * bv.y;
        o[jj * 4 + 2] = cn * bv.z;  o[jj * 4 + 3] = cn * bv.w;
    }
#pragma unroll
    for (int f = 0; f < 16; ++f) {
        float fv = Frow[f];
#pragma unroll
        for (int jj = 0; jj < 16; ++jj)
            o[jj] += fv * w2s[f][c0 + jj];
    }
    uint4 p0, p1;
    p0.x = pack_bf(o[0] * inv,  o[1] * inv);
    p0.y = pack_bf(o[2] * inv,  o[3] * inv);
    p0.z = pack_bf(o[4] * inv,  o[5] * inv);
    p0.w = pack_bf(o[6] * inv,  o[7] * inv);
    p1.x = pack_bf(o[8] * inv,  o[9] * inv);
    p1.y = pack_bf(o[10] * inv, o[11] * inv);
    p1.z = pack_bf(o[12] * inv, o[13] * inv);
    p1.w = pack_bf(o[14] * inv, o[15] * inv);
    uint4* dst = (uint4*)(h + (size_t)(r0 + row) * D_DIM + c0);
    dst[0] = p0;
    dst[1] = p1;
}

// ---------------------------------------------------------------------------
// Padded-CSC fill: slot = atomicAdd(cur[c]) into segment c*128. No scan.
// ---------------------------------------------------------------------------
__global__ void fill_kernel(const int* __restrict__ eidx, const float* __restrict__ attr,
                            int* __restrict__ cur, int* __restrict__ src_s,
                            float* __restrict__ attr_s) {
    int e = blockIdx.x * 256 + threadIdx.x;
    if (e < E_EDGES) {
        int r = eidx[e];
        int c = eidx[E_EDGES + e];
        int pos = atomicAdd(&cur[c], 1);
        int slot = (c << 7) + pos;             // capacity 128/dest
        src_s[slot]  = r;
        attr_s[slot] = attr[e];
    }
}

// ---------------------------------------------------------------------------
// Gather: g[c] = sum_e h[src[e]] * attr[e]; padded-CSC addressing.
// ---------------------------------------------------------------------------
__global__ void gather_kernel(const bf16_t* __restrict__ h,
                              const int* __restrict__ cur,
                              const int* __restrict__ src_s,
                              const float* __restrict__ attr_s,
                              bf16_t* __restrict__ g) {
    int wid  = (blockIdx.x * blockDim.x + threadIdx.x) >> 6;
    int lane = threadIdx.x & 63;
    if (wid >= N_NODES) return;
    int half = lane >> 5;
    int l32  = lane & 31;
    int e0 = wid << 7;
    int e1 = e0 + cur[wid];

    float acc[8] = {};
    for (int base = e0; base < e1; base += 64) {
        int n = e1 - base; if (n > 64) n = 64;
        int   r_l = 0; float a_l = 0.f;
        if (lane < n) { r_l = src_s[base + lane]; a_l = attr_s[base + lane]; }
        int nn = (n + 15) & ~15;            // pad to 8 pair-iterations
        for (int q = 0; q < nn; q += 16) {
#pragma unroll
            for (int u = 0; u < 8; ++u) {
                int   sl = q + 2 * u + half;
                int   r  = __shfl(r_l, sl, 64);
                float a  = __shfl(a_l, sl, 64);
                uint4 v  = ((const uint4*)(h + (size_t)r * D_DIM))[l32];
                acc[0] += lo_bf(v.x) * a;  acc[1] += hi_bf(v.x) * a;
                acc[2] += lo_bf(v.y) * a;  acc[3] += hi_bf(v.y) * a;
                acc[4] += lo_bf(v.z) * a;  acc[5] += hi_bf(v.z) * a;
                acc[6] += lo_bf(v.w) * a;  acc[7] += hi_bf(v.w) * a;
            }
        }
    }
#pragma unroll
    for (int i = 0; i < 8; ++i) acc[i] += __shfl_xor(acc[i], 32, 64);

    if (half == 0) {
        uint4 o;
        o.x = pack_bf(acc[0], acc[1]);
        o.y = pack_bf(acc[2], acc[3]);
        o.z = pack_bf(acc[4], acc[5]);
        o.w = pack_bf(acc[6], acc[7]);
        ((uint4*)(g + (size_t)wid * D_DIM))[l32] = o;
    }
}

// ---------------------------------------------------------------------------
// GEMM v4 (r10, kept): h' = relu(g @ W), persistent-B, dual-M-tile waves.
// ---------------------------------------------------------------------------
__global__ void __launch_bounds__(256, 2)
gemm_relu_kernel(const bf16_t* __restrict__ g,
                 const bf16_t* __restrict__ Wt_hi,
                 const bf16_t* __restrict__ Wt_lo,
                 bf16_t* __restrict__ hdst, float* __restrict__ fdst) {
    __shared__ bf16_t Bs[64][512];           // 64 KB: [n][k: 0..255 hi | 256..511 lo]
    int tid  = threadIdx.x;
    int w    = tid >> 6;
    int lane = tid & 63;
    int quad = lane >> 4;
    int id16 = lane & 15;

    int d    = blockIdx.x;                   // 0..627
    int xcd  = d & 7;
    int base = (xcd < 4) ? xcd * 79 : 316 + (xcd - 4) * 78;
    int wg   = base + (d >> 3);
    int bx   = wg >> 2;                      // 0..156 row-panel
    int by   = wg & 3;                       // 0..3   col-slab
    int bn   = by * 64;
    int bm0  = bx * 128;                     // up to 20096: gbuf pad absorbs

    char* bs = (char*)Bs;

    {
        int tn0 = tid >> 4;
        int ts0 = tid & 15;
#pragma unroll
        for (int it = 0; it < 16; ++it) {
            int n   = tn0 + (it & 3) * 16;
            int seg = ts0 + (it >> 2) * 16;
            const bf16_t* src = (seg < 32 ? Wt_hi : Wt_lo)
                              + (size_t)(bn + n) * D_DIM + (seg & 31) * 8;
            unsigned off = (unsigned)(n * 1024 + seg * 16) ^ (unsigned)((n & 7) << 4);
            *(uint4*)(bs + off) = *(const uint4*)src;
        }
    }

    int r0 = bm0 + w * 32;
    short8 areg[2][8];
#pragma unroll
    for (int j = 0; j < 2; ++j) {
        const bf16_t* arow = g + (size_t)(r0 + j * 16 + id16) * D_DIM;
#pragma unroll
        for (int i = 0; i < 8; ++i)
            areg[j][i] = *(const short8*)(arow + i * 32 + quad * 8);
    }

    __syncthreads();                         // the only barrier

    unsigned swz   = (unsigned)((id16 & 7) << 4);
    unsigned nbase = (unsigned)(id16 * 1024);

    f32x4 acc[2][4];
#pragma unroll
    for (int j = 0; j < 2; ++j)
#pragma unroll
        for (int nt = 0; nt < 4; ++nt) acc[j][nt] = (f32x4){0.f, 0.f, 0.f, 0.f};

#pragma unroll
    for (int ks = 0; ks < 8; ++ks) {
        unsigned kb = ((unsigned)(ks * 64 + quad * 16)) ^ swz;
#pragma unroll
        for (int nt = 0; nt < 4; ++nt) {
            unsigned off = (unsigned)(nt * 16384) + nbase + kb;
            short8 bh = *(const short8*)(bs + off);         // hi plane
            short8 bl = *(const short8*)(bs + off + 512);   // lo plane
            acc[0][nt] = __builtin_amdgcn_mfma_f32_16x16x32_bf16(areg[0][ks], bh, acc[0][nt], 0, 0, 0);
            acc[0][nt] = __builtin_amdgcn_mfma_f32_16x16x32_bf16(areg[0][ks], bl, acc[0][nt], 0, 0, 0);
            acc[1][nt] = __builtin_amdgcn_mfma_f32_16x16x32_bf16(areg[1][ks], bh, acc[1][nt], 0, 0, 0);
            acc[1][nt] = __builtin_amdgcn_mfma_f32_16x16x32_bf16(areg[1][ks], bl, acc[1][nt], 0, 0, 0);
        }
    }

#pragma unroll
    for (int j = 0; j < 2; ++j) {
#pragma unroll
        for (int nt = 0; nt < 4; ++nt) {
#pragma unroll
            for (int r = 0; r < 4; ++r) {
                int m = r0 + j * 16 + quad * 4 + r;
                if (m < N_NODES) {
                    int n = bn + nt * 16 + id16;
                    float v = fmaxf(acc[j][nt][r], 0.f);
                    if (hdst) hdst[(size_t)m * D_DIM + n] = f2bf(v);
                    else      fdst[(size_t)m * D_DIM + n] = v;
                }
            }
        }
    }
}

extern "C" void kernel_launch(void* const* d_in, const int* in_sizes, int n_in,
                              void* d_out, int out_size, void* d_ws, size_t ws_size,
                              hipStream_t stream) {
    const float* init_m = (const float*)d_in[0];
    const int*   eidx   = (const int*)  d_in[1];
    const float* attr   = (const float*)d_in[2];
    const float* w1     = (const float*)d_in[3];
    const float* b1     = (const float*)d_in[4];
    const float* w2     = (const float*)d_in[5];
    const float* b2     = (const float*)d_in[6];
    const float* Wm     = (const float*)d_in[7];
    float* out = (float*)d_out;

    // Workspace layout (bytes):
    //   hbuf   @ 0            10,240,000
    //   gbuf   @ 10,240,000   10,289,152  (incl 96 zeroed pad rows @20,480,000)
    //   cur    @ 20,529,152       80,000  (zeroed; doubles as degree count)
    //   src_s  @ 20,609,152   10,240,000  (padded CSC: 128 slots/dest)
    //   attr_s @ 30,849,152   10,240,000
    //   Wt_hi  @ 41,089,152      131,072
    //   Wt_lo  @ 41,220,224      131,072
    //   Pt_hi  @ 41,351,296      131,072
    //   Pt_lo  @ 41,482,368      131,072   (total ~41.6 MB)
    char* ws = (char*)d_ws;
    bf16_t* hbuf   = (bf16_t*)ws;
    bf16_t* gbuf   = (bf16_t*)(ws + 10240000);
    int*    cur    = (int*)   (ws + 20529152);
    int*    src_s  = (int*)   (ws + 20609152);
    float*  attr_s = (float*) (ws + 30849152);
    bf16_t* Wt_hi  = (bf16_t*)(ws + 41089152);
    bf16_t* Wt_lo  = (bf16_t*)(ws + 41220224);
    bf16_t* Pt_hi  = (bf16_t*)(ws + 41351296);
    bf16_t* Pt_lo  = (bf16_t*)(ws + 41482368);

    // single memset covers gbuf pad rows + cur
    hipMemsetAsync(ws + 20480000, 0, 129152, stream);

    // P table (consumed by mega's h0 branch)
    pphi_kernel<<<16, 256, 0, stream>>>(w1, b1, Pt_hi, Pt_lo);

    // front-end: h0 (mask-MFMA) + wsplit in one dispatch; then padded fill
    mega_kernel<<<1250 + 256, 256, 0, stream>>>(
        init_m, w2, b2, Pt_hi, Pt_lo, hbuf, Wm, Wt_hi, Wt_lo);
    fill_kernel<<<(E_EDGES + 255) / 256, 256, 0, stream>>>(eidx, attr, cur, src_s, attr_s);

    // 3x GCN layer: g = gather(h); h' = relu(g @ W)
    dim3 ggrid((N_NODES * 64 + 255) / 256);
    for (int it = 0; it < 3; ++it) {
        gather_kernel<<<ggrid, 256, 0, stream>>>(hbuf, cur, src_s, attr_s, gbuf);
        if (it == 2)
            gemm_relu_kernel<<<628, 256, 0, stream>>>(gbuf, Wt_hi, Wt_lo,
                                                      (bf16_t*)nullptr, out);
        else
            gemm_relu_kernel<<<628, 256, 0, stream>>>(gbuf, Wt_hi, Wt_lo,
                                                      hbuf, (float*)nullptr);
    }
}

// Round 14
// 633.814 us; speedup vs baseline: 2.0957x; 1.0296x over previous
//
#include <hip/hip_runtime.h>

// ============================================================================
// ROUND 14: final fusion — fill folded into mega (independent work, hides
// under h0's 327MB HBM read). Chain: memset -> pphi -> mega -> 3x(gather,
// gemm). Ledger after r13 (652.6): fills ~415 fixed (83% HBM peak), gather
// 95 (floor), gemm ~25 (floor), mega ~60-70 (HBM floor 52), fill ~15-20
// (this round: hidden), misc ~5. Prediction: 652.6 -> ~632-644, then the
// composed floor (~600) is within ~5% -> declare roofline.
// ============================================================================

#define N_NODES 20000
#define S_COLS  4096
#define E_EDGES 640000
#define D_DIM   256
#define DEG_CAP 128

typedef unsigned short bf16_t;
typedef __attribute__((ext_vector_type(8))) short short8;
typedef __attribute__((ext_vector_type(4))) float f32x4;

__device__ __forceinline__ float bf2f(bf16_t u) {
    union { unsigned int i; float f; } v; v.i = ((unsigned int)u) << 16; return v.f;
}
__device__ __forceinline__ bf16_t f2bf(float x) {   // round-to-nearest-even
    union { float f; unsigned int i; } v; v.f = x;
    unsigned int r = v.i + 0x7FFF + ((v.i >> 16) & 1);
    return (bf16_t)(r >> 16);
}
__device__ __forceinline__ float lo_bf(unsigned int u) {
    union { unsigned int i; float f; } v; v.i = u << 16; return v.f;
}
__device__ __forceinline__ float hi_bf(unsigned int u) {
    union { unsigned int i; float f; } v; v.i = u & 0xFFFF0000u; return v.f;
}
__device__ __forceinline__ unsigned int pack_bf(float a, float b) {
    return (unsigned int)f2bf(a) | ((unsigned int)f2bf(b) << 16);
}

// ---------------------------------------------------------------------------
// P precompute: Pt_hi/Pt_lo [16][4096] bf16, phi(j)[f] = relu(j*w1[f]+b1[f]).
// (Separate dispatch: mega's h0 blocks consume Pt, so ordering is needed.)
// ---------------------------------------------------------------------------
__global__ void pphi_kernel(const float* __restrict__ w1, const float* __restrict__ b1,
                            bf16_t* __restrict__ Pt_hi, bf16_t* __restrict__ Pt_lo) {
    int j = blockIdx.x * 256 + threadIdx.x;        // 0..4095
    float jf = (float)j;
#pragma unroll
    for (int f = 0; f < 16; ++f) {
        float phi = fmaxf(jf * w1[f] + b1[f], 0.f);
        bf16_t hi = f2bf(phi);
        bf16_t lo = f2bf(phi - bf2f(hi));
        Pt_hi[f * S_COLS + j] = hi;
        Pt_lo[f * S_COLS + j] = lo;
    }
}

// ---------------------------------------------------------------------------
// MEGA front-end: [0,1250) h0 mask-MFMA, [1250,1506) wsplit,
// [1506,4006) padded-CSC fill (hides under h0's HBM read).
// ---------------------------------------------------------------------------
__global__ void __launch_bounds__(256, 4)
mega_kernel(const float* __restrict__ init_m,
            const float* __restrict__ w2, const float* __restrict__ b2,
            const bf16_t* __restrict__ Pt_hi, const bf16_t* __restrict__ Pt_lo,
            bf16_t* __restrict__ h,
            const float* __restrict__ W,
            bf16_t* __restrict__ Wt_hi, bf16_t* __restrict__ Wt_lo,
            const int* __restrict__ eidx, const float* __restrict__ attr,
            int* __restrict__ cur, int* __restrict__ src_s,
            float* __restrict__ attr_s) {
    int b = blockIdx.x;
    int t = threadIdx.x;

    if (b >= 1250) {
        int bb = b - 1250;
        if (bb < 256) {                        // ---- wsplit ----
            int k = bb;                        // 0..255
            float w = W[k * D_DIM + t];
            bf16_t hi = f2bf(w);
            bf16_t lo = f2bf(w - bf2f(hi));
            Wt_hi[t * D_DIM + k] = hi;
            Wt_lo[t * D_DIM + k] = lo;
        } else {                               // ---- padded-CSC fill ----
            int e = (bb - 256) * 256 + t;      // 2500 blocks x 256 = 640000
            int r = eidx[e];
            int c = eidx[E_EDGES + e];
            int pos = atomicAdd(&cur[c], 1);
            int slot = (c << 7) + pos;         // capacity 128/dest
            src_s[slot]  = r;
            attr_s[slot] = attr[e];
        }
        return;
    }

    // ---- h0 mask-MFMA: F = mask @ [P_hi;P_lo], cnt = mask @ ones ----
    __shared__ float w2s[16][256];             // 16 KB
    __shared__ float Fred[4][16][16];          // 4 KB
    __shared__ float Cred[4][16];              // 256 B

#pragma unroll
    for (int k = 0; k < 16; ++k) w2s[k][t] = w2[k * D_DIM + t];

    int wave = t >> 6, lane = t & 63;
    int quad = lane >> 4, id16 = lane & 15;
    int r0 = b * 16;                           // 1250*16 = 20000 exactly

    const float*  arow = init_m + (size_t)(r0 + id16) * S_COLS + wave * 1024 + quad * 8;
    const bf16_t* bph  = Pt_hi + id16 * S_COLS + wave * 1024 + quad * 8;
    const bf16_t* bpl  = Pt_lo + id16 * S_COLS + wave * 1024 + quad * 8;

    short8 bones;
    short ov = (id16 == 0) ? (short)0x3F80 : (short)0;
#pragma unroll
    for (int i = 0; i < 8; ++i) bones[i] = ov;

    f32x4 accF = (f32x4){0.f, 0.f, 0.f, 0.f};
    f32x4 accC = (f32x4){0.f, 0.f, 0.f, 0.f};

    const short M1 = (short)0x3F80;            // bf16 1.0
#pragma unroll 4
    for (int s = 0; s < 32; ++s) {
        float4 x0 = *(const float4*)(arow + s * 32);
        float4 x1 = *(const float4*)(arow + s * 32 + 4);
        short8 bh = *(const short8*)(bph + s * 32);
        short8 bl = *(const short8*)(bpl + s * 32);
        short8 a;
        a[0] = (x0.x != 0.f) ? M1 : (short)0;
        a[1] = (x0.y != 0.f) ? M1 : (short)0;
        a[2] = (x0.z != 0.f) ? M1 : (short)0;
        a[3] = (x0.w != 0.f) ? M1 : (short)0;
        a[4] = (x1.x != 0.f) ? M1 : (short)0;
        a[5] = (x1.y != 0.f) ? M1 : (short)0;
        a[6] = (x1.z != 0.f) ? M1 : (short)0;
        a[7] = (x1.w != 0.f) ? M1 : (short)0;
        accF = __builtin_amdgcn_mfma_f32_16x16x32_bf16(a, bh, accF, 0, 0, 0);
        accF = __builtin_amdgcn_mfma_f32_16x16x32_bf16(a, bl, accF, 0, 0, 0);
        accC = __builtin_amdgcn_mfma_f32_16x16x32_bf16(a, bones, accC, 0, 0, 0);
    }

    // write partials (C/D layout: col=id16, row=quad*4+r)
#pragma unroll
    for (int r = 0; r < 4; ++r)
        Fred[wave][quad * 4 + r][id16] = accF[r];
    if (id16 == 0) {
#pragma unroll
        for (int r = 0; r < 4; ++r)
            Cred[wave][quad * 4 + r] = accC[r];
    }
    __syncthreads();

    // reduce + project: thread t -> row = t>>4, col-group cg = t&15
    int row = t >> 4, cg = t & 15;
    float Frow[16];
#pragma unroll
    for (int f = 0; f < 16; ++f)
        Frow[f] = Fred[0][row][f] + Fred[1][row][f] + Fred[2][row][f] + Fred[3][row][f];
    float cn = Cred[0][row] + Cred[1][row] + Cred[2][row] + Cred[3][row];
    float inv = 1.f / fmaxf(cn, 1.f);

    int c0 = cg * 16;
    float o[16];
#pragma unroll
    for (int jj = 0; jj < 4; ++jj) {
        float4 bv = *(const float4*)(b2 + c0 + jj * 4);
        o[jj * 4 + 0] = cn * bv.x;  o[jj * 4 + 1] = cn * bv.y;
        o[jj * 4 + 2] = cn * bv.z;  o[jj * 4 + 3] = cn * bv.w;
    }
#pragma unroll
    for (int f = 0; f < 16; ++f) {
        float fv = Frow[f];
#pragma unroll
        for (int jj = 0; jj < 16; ++jj)
            o[jj] += fv * w2s[f][c0 + jj];
    }
    uint4 p0, p1;
    p0.x = pack_bf(o[0] * inv,  o[1] * inv);
    p0.y = pack_bf(o[2] * inv,  o[3] * inv);
    p0.z = pack_bf(o[4] * inv,  o[5] * inv);
    p0.w = pack_bf(o[6] * inv,  o[7] * inv);
    p1.x = pack_bf(o[8] * inv,  o[9] * inv);
    p1.y = pack_bf(o[10] * inv, o[11] * inv);
    p1.z = pack_bf(o[12] * inv, o[13] * inv);
    p1.w = pack_bf(o[14] * inv, o[15] * inv);
    uint4* dst = (uint4*)(h + (size_t)(r0 + row) * D_DIM + c0);
    dst[0] = p0;
    dst[1] = p1;
}

// ---------------------------------------------------------------------------
// Gather: g[c] = sum_e h[src[e]] * attr[e]; padded-CSC addressing.
// ---------------------------------------------------------------------------
__global__ void gather_kernel(const bf16_t* __restrict__ h,
                              const int* __restrict__ cur,
                              const int* __restrict__ src_s,
                              const float* __restrict__ attr_s,
                              bf16_t* __restrict__ g) {
    int wid  = (blockIdx.x * blockDim.x + threadIdx.x) >> 6;
    int lane = threadIdx.x & 63;
    if (wid >= N_NODES) return;
    int half = lane >> 5;
    int l32  = lane & 31;
    int e0 = wid << 7;
    int e1 = e0 + cur[wid];

    float acc[8] = {};
    for (int base = e0; base < e1; base += 64) {
        int n = e1 - base; if (n > 64) n = 64;
        int   r_l = 0; float a_l = 0.f;
        if (lane < n) { r_l = src_s[base + lane]; a_l = attr_s[base + lane]; }
        int nn = (n + 15) & ~15;            // pad to 8 pair-iterations
        for (int q = 0; q < nn; q += 16) {
#pragma unroll
            for (int u = 0; u < 8; ++u) {
                int   sl = q + 2 * u + half;
                int   r  = __shfl(r_l, sl, 64);
                float a  = __shfl(a_l, sl, 64);
                uint4 v  = ((const uint4*)(h + (size_t)r * D_DIM))[l32];
                acc[0] += lo_bf(v.x) * a;  acc[1] += hi_bf(v.x) * a;
                acc[2] += lo_bf(v.y) * a;  acc[3] += hi_bf(v.y) * a;
                acc[4] += lo_bf(v.z) * a;  acc[5] += hi_bf(v.z) * a;
                acc[6] += lo_bf(v.w) * a;  acc[7] += hi_bf(v.w) * a;
            }
        }
    }
#pragma unroll
    for (int i = 0; i < 8; ++i) acc[i] += __shfl_xor(acc[i], 32, 64);

    if (half == 0) {
        uint4 o;
        o.x = pack_bf(acc[0], acc[1]);
        o.y = pack_bf(acc[2], acc[3]);
        o.z = pack_bf(acc[4], acc[5]);
        o.w = pack_bf(acc[6], acc[7]);
        ((uint4*)(g + (size_t)wid * D_DIM))[l32] = o;
    }
}

// ---------------------------------------------------------------------------
// GEMM v4 (r10, kept): h' = relu(g @ W), persistent-B, dual-M-tile waves.
// ---------------------------------------------------------------------------
__global__ void __launch_bounds__(256, 2)
gemm_relu_kernel(const bf16_t* __restrict__ g,
                 const bf16_t* __restrict__ Wt_hi,
                 const bf16_t* __restrict__ Wt_lo,
                 bf16_t* __restrict__ hdst, float* __restrict__ fdst) {
    __shared__ bf16_t Bs[64][512];           // 64 KB: [n][k: 0..255 hi | 256..511 lo]
    int tid  = threadIdx.x;
    int w    = tid >> 6;
    int lane = tid & 63;
    int quad = lane >> 4;
    int id16 = lane & 15;

    int d    = blockIdx.x;                   // 0..627
    int xcd  = d & 7;
    int base = (xcd < 4) ? xcd * 79 : 316 + (xcd - 4) * 78;
    int wg   = base + (d >> 3);
    int bx   = wg >> 2;                      // 0..156 row-panel
    int by   = wg & 3;                       // 0..3   col-slab
    int bn   = by * 64;
    int bm0  = bx * 128;                     // up to 20096: gbuf pad absorbs

    char* bs = (char*)Bs;

    {
        int tn0 = tid >> 4;
        int ts0 = tid & 15;
#pragma unroll
        for (int it = 0; it < 16; ++it) {
            int n   = tn0 + (it & 3) * 16;
            int seg = ts0 + (it >> 2) * 16;
            const bf16_t* src = (seg < 32 ? Wt_hi : Wt_lo)
                              + (size_t)(bn + n) * D_DIM + (seg & 31) * 8;
            unsigned off = (unsigned)(n * 1024 + seg * 16) ^ (unsigned)((n & 7) << 4);
            *(uint4*)(bs + off) = *(const uint4*)src;
        }
    }

    int r0 = bm0 + w * 32;
    short8 areg[2][8];
#pragma unroll
    for (int j = 0; j < 2; ++j) {
        const bf16_t* arow = g + (size_t)(r0 + j * 16 + id16) * D_DIM;
#pragma unroll
        for (int i = 0; i < 8; ++i)
            areg[j][i] = *(const short8*)(arow + i * 32 + quad * 8);
    }

    __syncthreads();                         // the only barrier

    unsigned swz   = (unsigned)((id16 & 7) << 4);
    unsigned nbase = (unsigned)(id16 * 1024);

    f32x4 acc[2][4];
#pragma unroll
    for (int j = 0; j < 2; ++j)
#pragma unroll
        for (int nt = 0; nt < 4; ++nt) acc[j][nt] = (f32x4){0.f, 0.f, 0.f, 0.f};

#pragma unroll
    for (int ks = 0; ks < 8; ++ks) {
        unsigned kb = ((unsigned)(ks * 64 + quad * 16)) ^ swz;
#pragma unroll
        for (int nt = 0; nt < 4; ++nt) {
            unsigned off = (unsigned)(nt * 16384) + nbase + kb;
            short8 bh = *(const short8*)(bs + off);         // hi plane
            short8 bl = *(const short8*)(bs + off + 512);   // lo plane
            acc[0][nt] = __builtin_amdgcn_mfma_f32_16x16x32_bf16(areg[0][ks], bh, acc[0][nt], 0, 0, 0);
            acc[0][nt] = __builtin_amdgcn_mfma_f32_16x16x32_bf16(areg[0][ks], bl, acc[0][nt], 0, 0, 0);
            acc[1][nt] = __builtin_amdgcn_mfma_f32_16x16x32_bf16(areg[1][ks], bh, acc[1][nt], 0, 0, 0);
            acc[1][nt] = __builtin_amdgcn_mfma_f32_16x16x32_bf16(areg[1][ks], bl, acc[1][nt], 0, 0, 0);
        }
    }

#pragma unroll
    for (int j = 0; j < 2; ++j) {
#pragma unroll
        for (int nt = 0; nt < 4; ++nt) {
#pragma unroll
            for (int r = 0; r < 4; ++r) {
                int m = r0 + j * 16 + quad * 4 + r;
                if (m < N_NODES) {
                    int n = bn + nt * 16 + id16;
                    float v = fmaxf(acc[j][nt][r], 0.f);
                    if (hdst) hdst[(size_t)m * D_DIM + n] = f2bf(v);
                    else      fdst[(size_t)m * D_DIM + n] = v;
                }
            }
        }
    }
}

extern "C" void kernel_launch(void* const* d_in, const int* in_sizes, int n_in,
                              void* d_out, int out_size, void* d_ws, size_t ws_size,
                              hipStream_t stream) {
    const float* init_m = (const float*)d_in[0];
    const int*   eidx   = (const int*)  d_in[1];
    const float* attr   = (const float*)d_in[2];
    const float* w1     = (const float*)d_in[3];
    const float* b1     = (const float*)d_in[4];
    const float* w2     = (const float*)d_in[5];
    const float* b2     = (const float*)d_in[6];
    const float* Wm     = (const float*)d_in[7];
    float* out = (float*)d_out;

    // Workspace layout (bytes):
    //   hbuf   @ 0            10,240,000
    //   gbuf   @ 10,240,000   10,289,152  (incl 96 zeroed pad rows @20,480,000)
    //   cur    @ 20,529,152       80,000  (zeroed; doubles as degree count)
    //   src_s  @ 20,609,152   10,240,000  (padded CSC: 128 slots/dest)
    //   attr_s @ 30,849,152   10,240,000
    //   Wt_hi  @ 41,089,152      131,072
    //   Wt_lo  @ 41,220,224      131,072
    //   Pt_hi  @ 41,351,296      131,072
    //   Pt_lo  @ 41,482,368      131,072   (total ~41.6 MB)
    char* ws = (char*)d_ws;
    bf16_t* hbuf   = (bf16_t*)ws;
    bf16_t* gbuf   = (bf16_t*)(ws + 10240000);
    int*    cur    = (int*)   (ws + 20529152);
    int*    src_s  = (int*)   (ws + 20609152);
    float*  attr_s = (float*) (ws + 30849152);
    bf16_t* Wt_hi  = (bf16_t*)(ws + 41089152);
    bf16_t* Wt_lo  = (bf16_t*)(ws + 41220224);
    bf16_t* Pt_hi  = (bf16_t*)(ws + 41351296);
    bf16_t* Pt_lo  = (bf16_t*)(ws + 41482368);

    // single memset covers gbuf pad rows + cur
    hipMemsetAsync(ws + 20480000, 0, 129152, stream);

    // P table (consumed by mega's h0 branch — ordering requires own dispatch)
    pphi_kernel<<<16, 256, 0, stream>>>(w1, b1, Pt_hi, Pt_lo);

    // front-end: h0 (mask-MFMA) + wsplit + padded fill, all in one dispatch
    mega_kernel<<<1250 + 256 + 2500, 256, 0, stream>>>(
        init_m, w2, b2, Pt_hi, Pt_lo, hbuf, Wm, Wt_hi, Wt_lo,
        eidx, attr, cur, src_s, attr_s);

    // 3x GCN layer: g = gather(h); h' = relu(g @ W)
    dim3 ggrid((N_NODES * 64 + 255) / 256);
    for (int it = 0; it < 3; ++it) {
        gather_kernel<<<ggrid, 256, 0, stream>>>(hbuf, cur, src_s, attr_s, gbuf);
        if (it == 2)
            gemm_relu_kernel<<<628, 256, 0, stream>>>(gbuf, Wt_hi, Wt_lo,
                                                      (bf16_t*)nullptr, out);
        else
            gemm_relu_kernel<<<628, 256, 0, stream>>>(gbuf, Wt_hi, Wt_lo,
                                                      hbuf, (float*)nullptr);
    }
}